// Round 9
// baseline (109.689 us; speedup 1.0000x reference)
//
#include <hip/hip_runtime.h>

// y: [B=8, C=192, H=64, W=64] f32; codebooks: [G=8, K=512, d=24] f32
// out (f32, concat): universal_ctx | y_ba | code_index [B,1,G,H,W]
// Stage prebuilds per-group f16 eh-images in ws (32 KiB/group, 256 KiB total):
// k<24 = f16-hi code fragments; k=24,25 cols (lanes 48..63) = exact-f64-derived
// f16 hi/lo of ||e||^2. Main: eh copied to LDS, el (f16 residuals) built from
// cb with zeroed k>=24 lanes; screen = 3 f16 MFMAs per t with X[q=3]=(1,1,0..)
// so e2 rides the matrix op. Per-(tile,r)-slot top-2 insertion (med3+min, 5-bit
// in-loop id = t), exact slot-merge to global top-3 at tail. Gate 2 quanta +
// <64 guard -> rare exact-f64 recheck.
#define B_   8
#define C_   192
#define HW_  4096
#define G_   8
#define K_   512
#define D_   24
#define CBSZ (K_ * D_)
#define THREADS 1024             // 16 waves/block
#define NBLOCKS 512              // 2 blocks/CU; 64 blocks/group; 1 pair/wave

// halfword units: eh frag 32 t * 512 = 16384; el frag same (k>=24 lanes zero)
#define EH_HW    16384
#define EL_OFF   16384
#define LDS_HW   32768           // 65536 B -> 2 blocks/CU (128 KiB of 160)
#define WS_G_HW  16384           // ws: 8 * 32768 B = 262144 B (256 KiB exactly)

typedef float  f32x4 __attribute__((ext_vector_type(4)));
typedef int    i32x4 __attribute__((ext_vector_type(4)));
typedef short  s16x8 __attribute__((ext_vector_type(8)));
typedef short  s16x4 __attribute__((ext_vector_type(4)));
typedef _Float16 h16x8 __attribute__((ext_vector_type(8)));
typedef unsigned long long u64;

static __device__ __forceinline__ unsigned umin_(unsigned a, unsigned b){return a<b?a:b;}
static __device__ __forceinline__ unsigned umax_(unsigned a, unsigned b){return a>b?a:b;}
// packed id9 = t<<4 | r<<2 | q  ->  code number = t*16 + q*4 + r
static __device__ __forceinline__ int dec_id(unsigned idb){
    return (int)((idb & 0x1F0u) | ((idb & 3u) << 2) | ((idb >> 2) & 3u));
}
static __device__ __forceinline__ unsigned pkrtz(float a, float b){
    return __builtin_bit_cast(unsigned, __builtin_amdgcn_cvt_pkrtz(a, b));
}
static __device__ __forceinline__ float lo16f(unsigned w){
    return (float)__builtin_bit_cast(_Float16, (unsigned short)(w & 0xFFFFu));
}
static __device__ __forceinline__ float hi16f(unsigned w){
    return (float)__builtin_bit_cast(_Float16, (unsigned short)(w >> 16));
}

// ---------- stage: build per-group eh images (with e2 hi/lo cols) in ws ----------
__global__ __launch_bounds__(256) void vq_stage(
    const float* __restrict__ cb, unsigned short* __restrict__ ws)
{
    const int g = blockIdx.x >> 3;
    const int s = blockIdx.x & 7;              // 64-code slice of this group
    const int tid = threadIdx.x;
    const float* cbg = cb + g * CBSZ;
    unsigned short* img = ws + g * WS_G_HW;

    for (int i = tid; i < 384; i += 256) {
        int gi = s * 384 + i;
        f32x4 v = ((const f32x4*)cbg)[gi];
        int i4 = gi << 2;
        int n  = i4 / 24;                      // float4 never crosses a row
        int k0 = i4 - n * 24;
        int off = (n >> 4) * 512 + (((k0 >> 3) << 4) + (n & 15)) * 8 + (k0 & 7);
        s16x4 h;
        #pragma unroll
        for (int j = 0; j < 4; ++j)
            h[j] = __builtin_bit_cast(short, (_Float16)v[j]);
        *(s16x4*)(&img[off]) = h;              // 8B-aligned (k0&7 in {0,4})
    }
    if (tid < 64) {                            // e2 hi/lo cols at k=24,25
        int n = s * 64 + tid;
        const float* row = cbg + n * D_;
        double s0 = 0.0, s1 = 0.0;
        #pragma unroll
        for (int j = 0; j < D_; j += 2) {
            double v0 = (double)row[j], v1 = (double)row[j+1];
            s0 = fma(v0,v0,s0); s1 = fma(v1,v1,s1);
        }
        double e2 = s0 + s1;                   // exact-ish ||e||^2
        _Float16 hi = (_Float16)(float)e2;
        _Float16 lo = (_Float16)(float)(e2 - (double)(float)hi);
        s16x8 pack = { __builtin_bit_cast(short, hi),
                       __builtin_bit_cast(short, lo), 0,0,0,0,0,0 };
        *(s16x8*)(&img[(n >> 4) * 512 + (48 + (n & 15)) * 8]) = pack;
    }
}

// ------------------------------- main kernel ---------------------------------
__global__ __launch_bounds__(THREADS, 8) void vq_main(
    const float* __restrict__ y, const float* __restrict__ cb,
    const unsigned short* __restrict__ ws, float* __restrict__ out)
{
    __shared__ __align__(16) unsigned short sB[LDS_HW];   // 65536 B

    const int bid = blockIdx.x;
    const int g = bid & 7;                     // group pinned to one XCD
    const int blkg = bid >> 3;                 // 64 blocks per group
    const int tid = threadIdx.x;
    const int wave = tid >> 6, lane = tid & 63;
    const int c = lane & 15, q = lane >> 4;

    const float* cbg = cb + g * CBSZ;

    // ---- staging: eh coalesced copy (32768 B, exactly 2 sweeps) ----
    {
        const char* src = (const char*)(ws + g * WS_G_HW);
        char* dst = (char*)sB;
        *(i32x4*)(dst + tid*16)         = *(const i32x4*)(src + tid*16);
        *(i32x4*)(dst + 16384 + tid*16) = *(const i32x4*)(src + 16384 + tid*16);
    }
    // ---- el: f16 residuals built from cb (coalesced, L2-hot) ----
    #pragma unroll
    for (int it = 0; it < 3; ++it) {
        int gi = it * THREADS + tid;           // 3072 float4s cover the group
        f32x4 v = ((const f32x4*)cbg)[gi];
        int i4 = gi << 2;
        int n  = i4 / 24;
        int k0 = i4 - n * 24;
        int off = (n >> 4) * 512 + (((k0 >> 3) << 4) + (n & 15)) * 8 + (k0 & 7);
        s16x4 l;
        #pragma unroll
        for (int j = 0; j < 4; ++j) {
            _Float16 eh = (_Float16)v[j];      // must match stage's RNE eh
            l[j] = __builtin_bit_cast(short, (_Float16)(v[j] - (float)eh));
        }
        *(s16x4*)(&sB[EL_OFF + off]) = l;
    }
    // zero el's k=24..31 lanes (they multiply X[q=3]=(1,1,..) -- must be 0)
    if (tid < 512) {
        int t = tid >> 4, cc = tid & 15;
        s16x8 z = {0,0,0,0,0,0,0,0};
        *(s16x8*)(&sB[EL_OFF + t * 512 + (48 + cc) * 8]) = z;
    }
    __syncthreads();

    float* out0 = out;
    float* out1 = out + B_*C_*HW_;
    float* out2 = out + 2*B_*C_*HW_;

    const unsigned short* aH = sB + lane * 8;            // stride 512 hw / t
    const unsigned short* aL = sB + EL_OFF + lane * 8;   // stride 512 hw / t

    const int wsid = (blkg << 4) + wave;       // [0,1024) per group
    const int hw    = (wsid & 255) << 4;
    const int bimg0 = wsid >> 8;               // 0..3; pair = (bimg0, bimg0+4)
    int ybase[2];
    ybase[0] = (bimg0*C_ + g*D_)*HW_ + hw;
    ybase[1] = ybase[0] + 4*C_*HW_;

    // ---- B operands: lane (c,q<3) holds (-2x)[pos c][k=q*8+j];
    //      q==3 -> Xh=(1,1,0,..) to pick up e2 hi/lo, Xl=0 ----
    h16x8 Xh[2], Xl[2];
    #pragma unroll
    for (int ti = 0; ti < 2; ++ti) {
        unsigned hx[4], lx[4];
        if (q < 3) {
            const float* yq = y + ybase[ti] + (q*8)*HW_ + c;
            float xf[8];
            #pragma unroll
            for (int jj = 0; jj < 8; ++jj) xf[jj] = -2.0f * yq[jj*HW_];
            #pragma unroll
            for (int p2 = 0; p2 < 4; ++p2) {
                float f0 = xf[2*p2], f1 = xf[2*p2+1];
                unsigned hw32 = pkrtz(f0, f1);            // RTZ: residual exact
                float r0 = f0 - lo16f(hw32), r1 = f1 - hi16f(hw32);
                hx[p2] = hw32;
                lx[p2] = pkrtz(r0, r1);
            }
        } else {
            hx[0]=0x3C003C00u; hx[1]=0u; hx[2]=0u; hx[3]=0u;   // (1.0h, 1.0h)
            lx[0]=0u; lx[1]=0u; lx[2]=0u; lx[3]=0u;
        }
        Xh[ti] = __builtin_bit_cast(h16x8, (i32x4){(int)hx[0],(int)hx[1],(int)hx[2],(int)hx[3]});
        Xl[ti] = __builtin_bit_cast(h16x8, (i32x4){(int)lx[0],(int)lx[1],(int)lx[2],(int)lx[3]});
    }

    const f32x4 cbias = {128.0f, 128.0f, 128.0f, 128.0f};

    // ---- fused 3-product f16 screen; per-(tile,r)-slot top-2 (med3+min).
    //      In-loop id = t (5 bits, inline const); quantum = 2^-5 mant bits. ----
    unsigned p1[2][4], p2[2][4];
    #pragma unroll
    for (int ti = 0; ti < 2; ++ti)
        #pragma unroll
        for (int r = 0; r < 4; ++r) { p1[ti][r] = ~0u; p2[ti][r] = ~0u; }

    #pragma unroll
    for (int t = 0; t < 32; ++t) {
        h16x8 eh = __builtin_bit_cast(h16x8, *(const s16x8*)(aH + t * 512));
        h16x8 el = __builtin_bit_cast(h16x8, *(const s16x8*)(aL + t * 512));
        f32x4 a0 = __builtin_amdgcn_mfma_f32_16x16x32_f16(eh, Xh[0], cbias, 0,0,0);
        a0       = __builtin_amdgcn_mfma_f32_16x16x32_f16(eh, Xl[0], a0,   0,0,0);
        a0       = __builtin_amdgcn_mfma_f32_16x16x32_f16(el, Xh[0], a0,   0,0,0);
        f32x4 a1 = __builtin_amdgcn_mfma_f32_16x16x32_f16(eh, Xh[1], cbias, 0,0,0);
        a1       = __builtin_amdgcn_mfma_f32_16x16x32_f16(eh, Xl[1], a1,   0,0,0);
        a1       = __builtin_amdgcn_mfma_f32_16x16x32_f16(el, Xh[1], a1,   0,0,0);
        #pragma unroll
        for (int r = 0; r < 4; ++r) {
            {
                unsigned key = (__float_as_uint(a0[r]) & 0xFFFFFFE0u) | (unsigned)t;
                unsigned t2;
                asm("v_med3_u32 %0, %1, %2, %3" : "=v"(t2) : "v"(key), "v"(p1[0][r]), "v"(p2[0][r]));
                p2[0][r] = t2; p1[0][r] = umin_(p1[0][r], key);
            }
            {
                unsigned key = (__float_as_uint(a1[r]) & 0xFFFFFFE0u) | (unsigned)t;
                unsigned t2;
                asm("v_med3_u32 %0, %1, %2, %3" : "=v"(t2) : "v"(key), "v"(p1[1][r]), "v"(p2[1][r]));
                p2[1][r] = t2; p1[1][r] = umin_(p1[1][r], key);
            }
        }
    }

    // ---- per-tile tail ----
    #pragma unroll
    for (int ti = 0; ti < 2; ++ti) {
        // embed r: (key<<2)|r  (v_lshl_or); slots stay sorted (uniform shift)
        unsigned s1[4], s2[4];
        #pragma unroll
        for (int r = 0; r < 4; ++r) {
            s1[r] = (p1[ti][r] << 2) | (unsigned)r;
            s2[r] = (p2[ti][r] << 2) | (unsigned)r;
        }
        // exact merge of 4 sorted pairs -> global(lane) top-3
        // pairs (s1[0],s2[0])+(s1[1],s2[1]) -> A; (2)+(3) -> B; A+B -> top3
        unsigned A1,A2,A3, B1,B2,B3;
        {
            unsigned lo=umin_(s1[0],s1[1]), hi=umax_(s1[0],s1[1]);
            unsigned lo2=umin_(s2[0],s2[1]), hi2=umax_(s2[0],s2[1]);
            A1=lo; A2=umin_(hi,lo2); A3=umin_(umax_(hi,lo2),hi2);
        }
        {
            unsigned lo=umin_(s1[2],s1[3]), hi=umax_(s1[2],s1[3]);
            unsigned lo2=umin_(s2[2],s2[3]), hi2=umax_(s2[2],s2[3]);
            B1=lo; B2=umin_(hi,lo2); B3=umin_(umax_(hi,lo2),hi2);
        }
        unsigned w1=umin_(A1,B1), z1=umax_(A1,B1);
        unsigned w2=umin_(A2,B2), z2=umax_(A2,B2);
        unsigned w3=umin_(A3,B3);
        unsigned m1 = w1;
        unsigned m2 = umin_(z1,w2);
        unsigned m3 = umin_(umin_(umax_(z1,w2), z2), w3);   // -> v_min3

        // embed q: final 9-bit id = t<<4 | r<<2 | q (monotone for our range)
        unsigned b1 = (m1 << 2) | (unsigned)q;
        unsigned b2 = (m2 << 2) | (unsigned)q;
        unsigned b3 = (m3 << 2) | (unsigned)q;
        #pragma unroll
        for (int d = 16; d < 64; d <<= 1) {    // butterfly: global top-3
            unsigned o1=__shfl_xor(b1,d,64), o2=__shfl_xor(b2,d,64), o3=__shfl_xor(b3,d,64);
            unsigned x = umax_(b1,o1);
            unsigned yv= umin_(b2,o2);
            unsigned w = umax_(b2,o2);
            unsigned z = umin_(b3,o3);
            b1 = umin_(b1,o1);
            b2 = umin_(x,yv);
            b3 = umin_(umax_(x,yv), umin_(w,z));
        }

        // gate: fire if int-gap < 2 quanta, or winner below 64.0
        // (b = accbits<<4 | id9; b>>9 = quantized value; 64.0f<<4 = 0x28000000)
        const int gap = (int)((b2 >> 9) - (b1 >> 9));
        int kwin;
        if (__ballot((gap < 2) || (b1 < 0x28000000u)) == 0ull) {
            kwin = dec_id(b1 & 511u);
        } else {
            // exact fp64 recheck (rare): re-derive -2x from y (cache-hot)
            float xfr[8];
            if (q < 3) {
                const float* yq = y + ybase[ti] + (q*8)*HW_ + c;
                #pragma unroll
                for (int jj = 0; jj < 8; ++jj) xfr[jj] = -2.0f * yq[jj*HW_];
            } else {
                #pragma unroll
                for (int jj = 0; jj < 8; ++jj) xfr[jj] = 0.0f;
            }
            double xd[8];
            #pragma unroll
            for (int jj = 0; jj < 8; ++jj) xd[jj] = (double)xfr[jj];
            const unsigned cands[3] = {b1, b2, b3};
            u64 bestk = ~0ull;
            #pragma unroll
            for (int ci = 0; ci < 3; ++ci) {
                int kc = dec_id(cands[ci] & 511u);
                double s = 0.0;
                if (q < 3) {
                    const f32x4* ce4 = (const f32x4*)(cbg + kc*D_ + (q<<3));
                    float ef[8];
                    *(f32x4*)&ef[0] = ce4[0];
                    *(f32x4*)&ef[4] = ce4[1];
                    #pragma unroll
                    for (int jj = 0; jj < 8; ++jj) {
                        double ev = (double)ef[jj];
                        s = fma(ev, ev, s);
                        s = fma(xd[jj], ev, s);
                    }
                }
                s += __shfl_xor(s, 16, 64);
                s += __shfl_xor(s, 32, 64);
                s += 128.0;
                u64 kk = (((u64)__double_as_longlong(s)) & ~0x1FFull) | (u64)kc;
                bestk = kk < bestk ? kk : bestk;
            }
            kwin = (int)(bestk & 511ull);
        }

        // epilogue: lane (c,q<3) writes dims q*8..q*8+7 of pos c
        const float* cw = cbg + kwin * D_;
        if (q < 3) {
            const f32x4* cw4 = (const f32x4*)(cw + (q<<3));
            float v[8];
            *(f32x4*)&v[0] = cw4[0];
            *(f32x4*)&v[4] = cw4[1];
            const int ob = ybase[ti] + (q*8)*HW_ + c;
            #pragma unroll
            for (int jj = 0; jj < 8; ++jj) {
                out0[ob + jj*HW_] = v[jj];
                out1[ob + jj*HW_] = v[jj];
            }
        }
        if (lane < 16) {
            const int bimg = bimg0 + 4*ti;
            out2[(bimg*G_ + g)*HW_ + hw + lane] = (float)kwin;
        }
    }
}

extern "C" void kernel_launch(void* const* d_in, const int* in_sizes, int n_in,
                              void* d_out, int out_size, void* d_ws, size_t ws_size,
                              hipStream_t stream) {
    const float* y  = (const float*)d_in[0];
    const float* cb = (const float*)d_in[1];
    float* out = (float*)d_out;
    unsigned short* ws = (unsigned short*)d_ws;   // needs 256 KiB

    vq_stage<<<dim3(64), dim3(256), 0, stream>>>(cb, ws);
    vq_main<<<dim3(NBLOCKS), dim3(THREADS), 0, stream>>>(y, cb, ws, out);
}

// Round 10
// 106.287 us; speedup vs baseline: 1.0320x; 1.0320x over previous
//
#include <hip/hip_runtime.h>

// y: [B=8, C=192, H=64, W=64] f32; codebooks: [G=8, K=512, d=24] f32
// out (f32, concat): universal_ctx | y_ba | code_index [B,1,G,H,W]
// Stage prebuilds per-group f16 eh-images in ws (32 KiB/group, 256 KiB total):
// k<24 = f16 code fragments; k=24,25 cols (lanes 48..63) = exact-f64-derived
// f16 hi/lo of ||e||^2. Main: eh in LDS (32 KiB); screen = 2 f16 MFMAs per t
// (eh*Xh + eh*Xl; X[q=3]=(1,1,0..) picks up e2). One ds_read_b128 per t.
// Per-(tile,r)-slot top-2 insertion (med3+min, 5-bit id = t), exact slot-merge
// to global top-3. Gate 64 quanta (covers dropped el*x term, ~20 sigma) ->
// ~38%/tile exact-f64 recheck.
#define B_   8
#define C_   192
#define HW_  4096
#define G_   8
#define K_   512
#define D_   24
#define CBSZ (K_ * D_)
#define THREADS 1024             // 16 waves/block
#define NBLOCKS 512              // 2 blocks/CU; 64 blocks/group; 1 pair/wave

// halfword units: eh frag 32 t * 512 = 16384 (e2 cols embedded at lanes 48..63)
#define LDS_HW   16384           // 32768 B -> 2 blocks/CU (64 KiB of 160)
#define WS_G_HW  16384           // ws: 8 * 32768 B = 262144 B (256 KiB)

typedef float  f32x4 __attribute__((ext_vector_type(4)));
typedef int    i32x4 __attribute__((ext_vector_type(4)));
typedef short  s16x8 __attribute__((ext_vector_type(8)));
typedef short  s16x4 __attribute__((ext_vector_type(4)));
typedef _Float16 h16x8 __attribute__((ext_vector_type(8)));
typedef unsigned long long u64;

static __device__ __forceinline__ unsigned umin_(unsigned a, unsigned b){return a<b?a:b;}
static __device__ __forceinline__ unsigned umax_(unsigned a, unsigned b){return a>b?a:b;}
// packed id9 = t<<4 | r<<2 | q  ->  code number = t*16 + q*4 + r
static __device__ __forceinline__ int dec_id(unsigned idb){
    return (int)((idb & 0x1F0u) | ((idb & 3u) << 2) | ((idb >> 2) & 3u));
}
static __device__ __forceinline__ unsigned pkrtz(float a, float b){
    return __builtin_bit_cast(unsigned, __builtin_amdgcn_cvt_pkrtz(a, b));
}
static __device__ __forceinline__ float lo16f(unsigned w){
    return (float)__builtin_bit_cast(_Float16, (unsigned short)(w & 0xFFFFu));
}
static __device__ __forceinline__ float hi16f(unsigned w){
    return (float)__builtin_bit_cast(_Float16, (unsigned short)(w >> 16));
}

// ---------- stage: build per-group eh images (with e2 hi/lo cols) in ws ----------
__global__ __launch_bounds__(256) void vq_stage(
    const float* __restrict__ cb, unsigned short* __restrict__ ws)
{
    const int g = blockIdx.x >> 3;
    const int s = blockIdx.x & 7;              // 64-code slice of this group
    const int tid = threadIdx.x;
    const float* cbg = cb + g * CBSZ;
    unsigned short* img = ws + g * WS_G_HW;

    for (int i = tid; i < 384; i += 256) {
        int gi = s * 384 + i;
        f32x4 v = ((const f32x4*)cbg)[gi];
        int i4 = gi << 2;
        int n  = i4 / 24;                      // float4 never crosses a row
        int k0 = i4 - n * 24;
        int off = (n >> 4) * 512 + (((k0 >> 3) << 4) + (n & 15)) * 8 + (k0 & 7);
        s16x4 h;
        #pragma unroll
        for (int j = 0; j < 4; ++j)
            h[j] = __builtin_bit_cast(short, (_Float16)v[j]);
        *(s16x4*)(&img[off]) = h;              // 8B-aligned (k0&7 in {0,4})
    }
    if (tid < 64) {                            // e2 hi/lo cols at k=24,25
        int n = s * 64 + tid;
        const float* row = cbg + n * D_;
        double s0 = 0.0, s1 = 0.0;
        #pragma unroll
        for (int j = 0; j < D_; j += 2) {
            double v0 = (double)row[j], v1 = (double)row[j+1];
            s0 = fma(v0,v0,s0); s1 = fma(v1,v1,s1);
        }
        double e2 = s0 + s1;                   // exact-ish ||e||^2
        _Float16 hi = (_Float16)(float)e2;
        _Float16 lo = (_Float16)(float)(e2 - (double)(float)hi);
        s16x8 pack = { __builtin_bit_cast(short, hi),
                       __builtin_bit_cast(short, lo), 0,0,0,0,0,0 };
        *(s16x8*)(&img[(n >> 4) * 512 + (48 + (n & 15)) * 8]) = pack;
    }
}

// ------------------------------- main kernel ---------------------------------
__global__ __launch_bounds__(THREADS, 8) void vq_main(
    const float* __restrict__ y, const float* __restrict__ cb,
    const unsigned short* __restrict__ ws, float* __restrict__ out)
{
    __shared__ __align__(16) unsigned short sB[LDS_HW];   // 32768 B

    const int bid = blockIdx.x;
    const int g = bid & 7;                     // group pinned to one XCD
    const int blkg = bid >> 3;                 // 64 blocks per group
    const int tid = threadIdx.x;
    const int wave = tid >> 6, lane = tid & 63;
    const int c = lane & 15, q = lane >> 4;

    const float* cbg = cb + g * CBSZ;

    // ---- staging: eh coalesced copy (32768 B, exactly 2 sweeps) ----
    {
        const char* src = (const char*)(ws + g * WS_G_HW);
        char* dst = (char*)sB;
        *(i32x4*)(dst + tid*16)         = *(const i32x4*)(src + tid*16);
        *(i32x4*)(dst + 16384 + tid*16) = *(const i32x4*)(src + 16384 + tid*16);
    }
    __syncthreads();

    float* out0 = out;
    float* out1 = out + B_*C_*HW_;
    float* out2 = out + 2*B_*C_*HW_;

    const unsigned short* aH = sB + lane * 8;  // stride 512 hw / t

    const int wsid = (blkg << 4) + wave;       // [0,1024) per group
    const int hw    = (wsid & 255) << 4;
    const int bimg0 = wsid >> 8;               // 0..3; pair = (bimg0, bimg0+4)
    int ybase[2];
    ybase[0] = (bimg0*C_ + g*D_)*HW_ + hw;
    ybase[1] = ybase[0] + 4*C_*HW_;

    // ---- B operands: lane (c,q<3) holds (-2x)[pos c][k=q*8+j];
    //      q==3 -> Xh=(1,1,0,..) to pick up e2 hi/lo, Xl=0 ----
    h16x8 Xh[2], Xl[2];
    #pragma unroll
    for (int ti = 0; ti < 2; ++ti) {
        unsigned hx[4], lx[4];
        if (q < 3) {
            const float* yq = y + ybase[ti] + (q*8)*HW_ + c;
            float xf[8];
            #pragma unroll
            for (int jj = 0; jj < 8; ++jj) xf[jj] = -2.0f * yq[jj*HW_];
            #pragma unroll
            for (int p2 = 0; p2 < 4; ++p2) {
                float f0 = xf[2*p2], f1 = xf[2*p2+1];
                unsigned hw32 = pkrtz(f0, f1);            // RTZ: residual exact
                float r0 = f0 - lo16f(hw32), r1 = f1 - hi16f(hw32);
                hx[p2] = hw32;
                lx[p2] = pkrtz(r0, r1);
            }
        } else {
            hx[0]=0x3C003C00u; hx[1]=0u; hx[2]=0u; hx[3]=0u;   // (1.0h, 1.0h)
            lx[0]=0u; lx[1]=0u; lx[2]=0u; lx[3]=0u;
        }
        Xh[ti] = __builtin_bit_cast(h16x8, (i32x4){(int)hx[0],(int)hx[1],(int)hx[2],(int)hx[3]});
        Xl[ti] = __builtin_bit_cast(h16x8, (i32x4){(int)lx[0],(int)lx[1],(int)lx[2],(int)lx[3]});
    }

    const f32x4 cbias = {128.0f, 128.0f, 128.0f, 128.0f};

    // ---- 2-product f16 screen; per-(tile,r)-slot top-2 (med3+min).
    //      In-loop id = t (5 bits, inline const). 1 ds_read_b128 per t. ----
    unsigned p1[2][4], p2[2][4];
    #pragma unroll
    for (int ti = 0; ti < 2; ++ti)
        #pragma unroll
        for (int r = 0; r < 4; ++r) { p1[ti][r] = ~0u; p2[ti][r] = ~0u; }

    #pragma unroll
    for (int t = 0; t < 32; ++t) {
        h16x8 eh = __builtin_bit_cast(h16x8, *(const s16x8*)(aH + t * 512));
        f32x4 a0 = __builtin_amdgcn_mfma_f32_16x16x32_f16(eh, Xh[0], cbias, 0,0,0);
        a0       = __builtin_amdgcn_mfma_f32_16x16x32_f16(eh, Xl[0], a0,   0,0,0);
        f32x4 a1 = __builtin_amdgcn_mfma_f32_16x16x32_f16(eh, Xh[1], cbias, 0,0,0);
        a1       = __builtin_amdgcn_mfma_f32_16x16x32_f16(eh, Xl[1], a1,   0,0,0);
        #pragma unroll
        for (int r = 0; r < 4; ++r) {
            {
                unsigned key = (__float_as_uint(a0[r]) & 0xFFFFFFE0u) | (unsigned)t;
                unsigned t2;
                asm("v_med3_u32 %0, %1, %2, %3" : "=v"(t2) : "v"(key), "v"(p1[0][r]), "v"(p2[0][r]));
                p2[0][r] = t2; p1[0][r] = umin_(p1[0][r], key);
            }
            {
                unsigned key = (__float_as_uint(a1[r]) & 0xFFFFFFE0u) | (unsigned)t;
                unsigned t2;
                asm("v_med3_u32 %0, %1, %2, %3" : "=v"(t2) : "v"(key), "v"(p1[1][r]), "v"(p2[1][r]));
                p2[1][r] = t2; p1[1][r] = umin_(p1[1][r], key);
            }
        }
    }

    // ---- per-tile tail ----
    #pragma unroll
    for (int ti = 0; ti < 2; ++ti) {
        // embed r: (key<<2)|r; slots stay sorted (uniform shift)
        unsigned s1[4], s2[4];
        #pragma unroll
        for (int r = 0; r < 4; ++r) {
            s1[r] = (p1[ti][r] << 2) | (unsigned)r;
            s2[r] = (p2[ti][r] << 2) | (unsigned)r;
        }
        // exact merge of 4 sorted pairs -> per-lane top-3
        unsigned A1,A2,A3, B1,B2,B3;
        {
            unsigned lo=umin_(s1[0],s1[1]), hi=umax_(s1[0],s1[1]);
            unsigned lo2=umin_(s2[0],s2[1]), hi2=umax_(s2[0],s2[1]);
            A1=lo; A2=umin_(hi,lo2); A3=umin_(umax_(hi,lo2),hi2);
        }
        {
            unsigned lo=umin_(s1[2],s1[3]), hi=umax_(s1[2],s1[3]);
            unsigned lo2=umin_(s2[2],s2[3]), hi2=umax_(s2[2],s2[3]);
            B1=lo; B2=umin_(hi,lo2); B3=umin_(umax_(hi,lo2),hi2);
        }
        unsigned w1=umin_(A1,B1), z1=umax_(A1,B1);
        unsigned w2=umin_(A2,B2), z2=umax_(A2,B2);
        unsigned w3=umin_(A3,B3);
        unsigned m1 = w1;
        unsigned m2 = umin_(z1,w2);
        unsigned m3 = umin_(umin_(umax_(z1,w2), z2), w3);   // -> v_min3

        // embed q: final 9-bit id = t<<4 | r<<2 | q (monotone for our range)
        unsigned b1 = (m1 << 2) | (unsigned)q;
        unsigned b2 = (m2 << 2) | (unsigned)q;
        unsigned b3 = (m3 << 2) | (unsigned)q;
        #pragma unroll
        for (int d = 16; d < 64; d <<= 1) {    // butterfly: global top-3
            unsigned o1=__shfl_xor(b1,d,64), o2=__shfl_xor(b2,d,64), o3=__shfl_xor(b3,d,64);
            unsigned x = umax_(b1,o1);
            unsigned yv= umin_(b2,o2);
            unsigned w = umax_(b2,o2);
            unsigned z = umin_(b3,o3);
            b1 = umin_(b1,o1);
            b2 = umin_(x,yv);
            b3 = umin_(umax_(x,yv), umin_(w,z));
        }

        // gate: fire if int-gap < 64 quanta (~0.031 at exp 7) -- covers the
        // dropped el*x term (~1.5e-3 rms) with ~20-sigma margin. Values are
        // >= 128 (bias), so exponent >= 7 always; no small-value guard needed.
        const int gap = (int)((b2 >> 9) - (b1 >> 9));
        int kwin;
        if (__ballot(gap < 64) == 0ull) {
            kwin = dec_id(b1 & 511u);
        } else {
            // exact fp64 recheck: re-derive -2x from y (cache-hot)
            float xfr[8];
            if (q < 3) {
                const float* yq = y + ybase[ti] + (q*8)*HW_ + c;
                #pragma unroll
                for (int jj = 0; jj < 8; ++jj) xfr[jj] = -2.0f * yq[jj*HW_];
            } else {
                #pragma unroll
                for (int jj = 0; jj < 8; ++jj) xfr[jj] = 0.0f;
            }
            double xd[8];
            #pragma unroll
            for (int jj = 0; jj < 8; ++jj) xd[jj] = (double)xfr[jj];
            const unsigned cands[3] = {b1, b2, b3};
            u64 bestk = ~0ull;
            #pragma unroll
            for (int ci = 0; ci < 3; ++ci) {
                int kc = dec_id(cands[ci] & 511u);
                double s = 0.0;
                if (q < 3) {
                    const f32x4* ce4 = (const f32x4*)(cbg + kc*D_ + (q<<3));
                    float ef[8];
                    *(f32x4*)&ef[0] = ce4[0];
                    *(f32x4*)&ef[4] = ce4[1];
                    #pragma unroll
                    for (int jj = 0; jj < 8; ++jj) {
                        double ev = (double)ef[jj];
                        s = fma(ev, ev, s);
                        s = fma(xd[jj], ev, s);
                    }
                }
                s += __shfl_xor(s, 16, 64);
                s += __shfl_xor(s, 32, 64);
                s += 128.0;
                u64 kk = (((u64)__double_as_longlong(s)) & ~0x1FFull) | (u64)kc;
                bestk = kk < bestk ? kk : bestk;
            }
            kwin = (int)(bestk & 511ull);
        }

        // epilogue: lane (c,q<3) writes dims q*8..q*8+7 of pos c
        const float* cw = cbg + kwin * D_;
        if (q < 3) {
            const f32x4* cw4 = (const f32x4*)(cw + (q<<3));
            float v[8];
            *(f32x4*)&v[0] = cw4[0];
            *(f32x4*)&v[4] = cw4[1];
            const int ob = ybase[ti] + (q*8)*HW_ + c;
            #pragma unroll
            for (int jj = 0; jj < 8; ++jj) {
                out0[ob + jj*HW_] = v[jj];
                out1[ob + jj*HW_] = v[jj];
            }
        }
        if (lane < 16) {
            const int bimg = bimg0 + 4*ti;
            out2[(bimg*G_ + g)*HW_ + hw + lane] = (float)kwin;
        }
    }
}

extern "C" void kernel_launch(void* const* d_in, const int* in_sizes, int n_in,
                              void* d_out, int out_size, void* d_ws, size_t ws_size,
                              hipStream_t stream) {
    const float* y  = (const float*)d_in[0];
    const float* cb = (const float*)d_in[1];
    float* out = (float*)d_out;
    unsigned short* ws = (unsigned short*)d_ws;   // needs 256 KiB

    vq_stage<<<dim3(64), dim3(256), 0, stream>>>(cb, ws);
    vq_main<<<dim3(NBLOCKS), dim3(THREADS), 0, stream>>>(y, cb, ws, out);
}